// Round 2
// baseline (394.341 us; speedup 1.0000x reference)
//
#include <hip/hip_runtime.h>

#define S_DIM 4
#define A_DIM 64
#define B_DIM 2048
#define D_DIM 384
#define H1D 128
#define H2D 128
#define H3D 64
#define MT 64   // batch rows per block (4 waves x 16 rows)
#define XROW (A_DIM * D_DIM)   // x row stride in floats (98304 B)

typedef __attribute__((ext_vector_type(8))) short short8;
typedef __attribute__((ext_vector_type(4))) float float4v;

__device__ __forceinline__ unsigned short f2bf(float f) {
  unsigned u = __float_as_uint(f);
  u += 0x7FFFu + ((u >> 16) & 1u);   // round-to-nearest-even
  return (unsigned short)(u >> 16);
}

__device__ __forceinline__ short8 pack_bf8(float4v lo, float4v hi) {
  short8 o;
  o[0] = (short)f2bf(lo[0]); o[1] = (short)f2bf(lo[1]);
  o[2] = (short)f2bf(lo[2]); o[3] = (short)f2bf(lo[3]);
  o[4] = (short)f2bf(hi[0]); o[5] = (short)f2bf(hi[1]);
  o[6] = (short)f2bf(hi[2]); o[7] = (short)f2bf(hi[3]);
  return o;
}

// Intra-wave LDS fence: waves are fully independent here (no cross-wave LDS
// sharing), so ds_write -> fence -> ds_read within one wave is all the sync
// this kernel needs. The memory clobber stops compile-time reordering; the
// lgkmcnt(0) guarantees the writes have landed. NO s_barrier anywhere.
#define WAVE_LDS_FENCE() asm volatile("s_waitcnt lgkmcnt(0)" ::: "memory")

// LDS-tiled transpose + bf16 convert: coalesced reads AND writes.
// out layouts (N-major): W0T[s][h1][d], W1T[s][h2][h1], W2T[s][h3][h2]
__global__ __launch_bounds__(256) void prep_weights(
    const float* __restrict__ W0, const float* __restrict__ W1,
    const float* __restrict__ W2,
    unsigned short* __restrict__ W0T, unsigned short* __restrict__ W1T,
    unsigned short* __restrict__ W2T) {
  __shared__ float tile[32][33];
  int b = blockIdx.x;
  const float* src; unsigned short* dst; int R, C, dt, ht, s;
  if (b < 192) {                 // W0: 4 x 12 x 4 tiles
    s = b / 48; int t = b % 48; dt = t / 4; ht = t % 4;
    src = W0 + s * D_DIM * H1D; dst = W0T + s * H1D * D_DIM; R = D_DIM; C = H1D;
  } else if (b < 256) {          // W1: 4 x 4 x 4
    int bb = b - 192; s = bb / 16; int t = bb % 16; dt = t / 4; ht = t % 4;
    src = W1 + s * H1D * H2D; dst = W1T + s * H2D * H1D; R = H1D; C = H2D;
  } else {                       // W2: 4 x 4 x 2
    int bb = b - 256; s = bb / 8; int t = bb % 8; dt = t / 2; ht = t % 2;
    src = W2 + s * H2D * H3D; dst = W2T + s * H3D * H2D; R = H2D; C = H3D;
  }
  int tx = threadIdx.x & 31, ty = threadIdx.x >> 5;
#pragma unroll
  for (int k = 0; k < 4; ++k)
    tile[ty + 8 * k][tx] = src[(size_t)(dt * 32 + ty + 8 * k) * C + ht * 32 + tx];
  __syncthreads();
#pragma unroll
  for (int k = 0; k < 4; ++k)
    dst[(size_t)(ht * 32 + ty + 8 * k) * R + dt * 32 + tx] = f2bf(tile[tx][ty + 8 * k]);
}

// Barrier-free structure: each wave owns 16 batch rows x ALL columns.
//  - layer-0 A-frags load x straight from global (lane (q,r) reads its own
//    row's k-slice) -> no x LDS staging, x still read exactly once from HBM.
//  - H0/H1/H2 are per-wave LDS slices; every layer's A-frags come from rows
//    this wave wrote itself -> zero __syncthreads in the whole kernel.
//  - weights (bf16, N-major) are read per-wave from L2 (~590 KB resident).
// LDS 34 KB -> 4 blocks/CU; (256,4) caps VGPR at 128 -> 16 waves/CU.
__global__ __launch_bounds__(256, 4) void mlp_fused(
    const float* __restrict__ x, const int* __restrict__ species,
    const unsigned short* __restrict__ W0T, const unsigned short* __restrict__ W1T,
    const unsigned short* __restrict__ W2T,
    const float* __restrict__ b0, const float* __restrict__ b1,
    const float* __restrict__ b2, const float* __restrict__ W3,
    const float* __restrict__ b3, float* __restrict__ partial) {
  // 136-short row stride: 16B-aligned b128 reads, <=2-way bank aliasing (free).
  __shared__ __align__(16) unsigned short Hb0[4 * 16 * 136];  // per-wave H1
  __shared__ __align__(16) unsigned short Hb1[4 * 16 * 136];  // per-wave H0, then H2

  const int a = blockIdx.x;          // atom-major: dense device-wide x footprint
  const int brow0 = blockIdx.y * MT;
  const int sp = species[a];
  const int tid = threadIdx.x;
  const int w = tid >> 6;            // wave id: rows w*16 .. w*16+15
  const int lane = tid & 63;
  const int q = lane >> 4;   // A/B k-quad, C/D row-quad
  const int r = lane & 15;   // A row / B col / C col

  unsigned short* H0w = Hb1 + w * 16 * 136;   // bf16 [16][136]
  unsigned short* H1w = Hb0 + w * 16 * 136;   // bf16 [16][136]
  float* H2w = (float*)(Hb1 + w * 16 * 136);  // fp32 [16][68] (4352 B slice)

  const float4v zero = {0.f, 0.f, 0.f, 0.f};

  // ---------------- layer 0: x[16 rows x 384] @ W0[384 x 128] ----------------
  {
    const float* xb = x + ((size_t)(brow0 + w * 16 + r) * A_DIM + a) * D_DIM + q * 8;
    const unsigned short* w0b = W0T + (size_t)sp * H1D * D_DIM + r * D_DIM + q * 8;
    float4v acc0[8];
#pragma unroll
    for (int n = 0; n < 8; ++n) acc0[n] = zero;
#pragma unroll
    for (int c = 0; c < 3; ++c) {
      short8 af[4];
#pragma unroll
      for (int kk = 0; kk < 4; ++kk) {
        float4v lo = *(const float4v*)(xb + c * 128 + kk * 32);
        float4v hi = *(const float4v*)(xb + c * 128 + kk * 32 + 4);
        af[kk] = pack_bf8(lo, hi);
      }
#pragma unroll
      for (int n = 0; n < 8; ++n)
#pragma unroll
        for (int kk = 0; kk < 4; ++kk) {
          short8 wf = *(const short8*)(w0b + (size_t)n * 16 * D_DIM + c * 128 + kk * 32);
          acc0[n] = __builtin_amdgcn_mfma_f32_16x16x32_bf16(af[kk], wf, acc0[n], 0, 0, 0);
        }
    }
    const float* b0p = b0 + sp * H1D;
#pragma unroll
    for (int n = 0; n < 8; ++n) {
      float bias = b0p[n * 16 + r];
#pragma unroll
      for (int i = 0; i < 4; ++i) {
        float y = acc0[n][i] + bias;
        H0w[(q * 4 + i) * 136 + n * 16 + r] = f2bf(__expf(-y * y));
      }
    }
  }
  WAVE_LDS_FENCE();   // H0w visible to this wave's layer-1 reads

  // ---------------- layer 1: H0[16x128] @ W1[128x128] ----------------
  {
    const unsigned short* w1b = W1T + (size_t)sp * H2D * H1D + r * H1D + q * 8;
    float4v acc1[8];
#pragma unroll
    for (int n = 0; n < 8; ++n) acc1[n] = zero;
    short8 af[4];
#pragma unroll
    for (int kk = 0; kk < 4; ++kk)
      af[kk] = *(const short8*)(H0w + r * 136 + kk * 32 + q * 8);
#pragma unroll
    for (int n = 0; n < 8; ++n)
#pragma unroll
      for (int kk = 0; kk < 4; ++kk) {
        short8 wf = *(const short8*)(w1b + (size_t)n * 16 * H1D + kk * 32);
        acc1[n] = __builtin_amdgcn_mfma_f32_16x16x32_bf16(af[kk], wf, acc1[n], 0, 0, 0);
      }
    const float* b1p = b1 + sp * H2D;
#pragma unroll
    for (int n = 0; n < 8; ++n) {
      float bias = b1p[n * 16 + r];
#pragma unroll
      for (int i = 0; i < 4; ++i) {
        float y = acc1[n][i] + bias;
        H1w[(q * 4 + i) * 136 + n * 16 + r] = f2bf(__expf(-y * y));
      }
    }
  }
  WAVE_LDS_FENCE();   // H1w visible; H0w slice now reusable as H2w

  // ---------------- layer 2: H1[16x128] @ W2[128x64] ----------------
  {
    const unsigned short* w2b = W2T + (size_t)sp * H3D * H2D + r * H2D + q * 8;
    float4v acc2[4];
#pragma unroll
    for (int n = 0; n < 4; ++n) acc2[n] = zero;
    short8 af[4];
#pragma unroll
    for (int kk = 0; kk < 4; ++kk)
      af[kk] = *(const short8*)(H1w + r * 136 + kk * 32 + q * 8);
#pragma unroll
    for (int n = 0; n < 4; ++n)
#pragma unroll
      for (int kk = 0; kk < 4; ++kk) {
        short8 wf = *(const short8*)(w2b + (size_t)n * 16 * H2D + kk * 32);
        acc2[n] = __builtin_amdgcn_mfma_f32_16x16x32_bf16(af[kk], wf, acc2[n], 0, 0, 0);
      }
    const float* b2p = b2 + sp * H3D;
#pragma unroll
    for (int n = 0; n < 4; ++n) {
      float bias = b2p[n * 16 + r];
#pragma unroll
      for (int i = 0; i < 4; ++i) {
        float y = acc2[n][i] + bias;
        H2w[(q * 4 + i) * 68 + n * 16 + r] = __expf(-y * y);
      }
    }
  }
  WAVE_LDS_FENCE();   // H2w visible

  // -------- layer 3: dot with W3[64]; non-atomic partial write --------
  // per wave: 16 contiguous floats (one 64B line), coalesced, no atomics.
  {
    const int row = lane >> 2;
    const int seg = lane & 3;
    const float4v* h2p = (const float4v*)(H2w + row * 68 + seg * 16);
    const float4v* w3p = (const float4v*)(W3 + sp * H3D + seg * 16);
    float4v sv = zero;
#pragma unroll
    for (int jj = 0; jj < 4; ++jj) sv += h2p[jj] * w3p[jj];
    float s = sv[0] + sv[1] + sv[2] + sv[3];
    s += __shfl_xor(s, 1);
    s += __shfl_xor(s, 2);
    if (seg == 0) partial[(size_t)a * B_DIM + brow0 + w * 16 + row] = s + b3[sp];
  }
}

// out[b] = sum_a partial[a][b]; 512 KB read (L2-hot), 8 KB write.
__global__ __launch_bounds__(256) void reduce_partial(
    const float* __restrict__ p, float* __restrict__ out) {
  const int b = blockIdx.x * 256 + threadIdx.x;
  float s = 0.f;
#pragma unroll
  for (int a = 0; a < A_DIM; ++a) s += p[(size_t)a * B_DIM + b];
  out[b] = s;
}

extern "C" void kernel_launch(void* const* d_in, const int* in_sizes, int n_in,
                              void* d_out, int out_size, void* d_ws, size_t ws_size,
                              hipStream_t stream) {
  const float* x       = (const float*)d_in[0];
  const int*   species = (const int*)d_in[1];
  const float* W0 = (const float*)d_in[2];
  const float* b0 = (const float*)d_in[3];
  const float* W1 = (const float*)d_in[4];
  const float* b1 = (const float*)d_in[5];
  const float* W2 = (const float*)d_in[6];
  const float* b2 = (const float*)d_in[7];
  const float* W3 = (const float*)d_in[8];
  const float* b3 = (const float*)d_in[9];
  float* out = (float*)d_out;

  unsigned short* W0T = (unsigned short*)d_ws;
  unsigned short* W1T = W0T + S_DIM * H1D * D_DIM;
  unsigned short* W2T = W1T + S_DIM * H2D * H1D;
  float* partial = (float*)(W2T + S_DIM * H3D * H2D);   // [A_DIM][B_DIM] fp32

  prep_weights<<<dim3(288), dim3(256), 0, stream>>>(W0, W1, W2, W0T, W1T, W2T);
  mlp_fused<<<dim3(A_DIM, B_DIM / MT), dim3(256), 0, stream>>>(
      x, species, W0T, W1T, W2T, b0, b1, b2, W3, b3, partial);
  reduce_partial<<<dim3(B_DIM / 256), dim3(256), 0, stream>>>(partial, out);
}

// Round 3
// 336.643 us; speedup vs baseline: 1.1714x; 1.1714x over previous
//
#include <hip/hip_runtime.h>

#define S_DIM 4
#define A_DIM 64
#define B_DIM 2048
#define D_DIM 384
#define H1D 128
#define H2D 128
#define H3D 64
#define MT 32   // batch rows per block (4 waves x 32 rows, waves split N)
#define XROW (A_DIM * D_DIM)   // x row stride in floats (98304 B)

typedef __attribute__((ext_vector_type(8))) short short8;
typedef __attribute__((ext_vector_type(4))) float float4v;

__device__ __forceinline__ unsigned short f2bf(float f) {
  unsigned u = __float_as_uint(f);
  u += 0x7FFFu + ((u >> 16) & 1u);   // round-to-nearest-even
  return (unsigned short)(u >> 16);
}

__device__ __forceinline__ void store_bf4(unsigned short* p, float4v v) {
  union { unsigned short s[4]; uint2 u; } t;
  t.s[0] = f2bf(v[0]); t.s[1] = f2bf(v[1]);
  t.s[2] = f2bf(v[2]); t.s[3] = f2bf(v[3]);
  *(uint2*)p = t.u;   // one ds_write_b64
}

// LDS-tiled transpose + bf16 convert: coalesced reads AND writes.
// out layouts (N-major): W0T[s][h1][d], W1T[s][h2][h1], W2T[s][h3][h2]
__global__ __launch_bounds__(256) void prep_weights(
    const float* __restrict__ W0, const float* __restrict__ W1,
    const float* __restrict__ W2,
    unsigned short* __restrict__ W0T, unsigned short* __restrict__ W1T,
    unsigned short* __restrict__ W2T) {
  __shared__ float tile[32][33];
  int b = blockIdx.x;
  const float* src; unsigned short* dst; int R, C, dt, ht, s;
  if (b < 192) {                 // W0: 4 x 12 x 4 tiles
    s = b / 48; int t = b % 48; dt = t / 4; ht = t % 4;
    src = W0 + s * D_DIM * H1D; dst = W0T + s * H1D * D_DIM; R = D_DIM; C = H1D;
  } else if (b < 256) {          // W1: 4 x 4 x 4
    int bb = b - 192; s = bb / 16; int t = bb % 16; dt = t / 4; ht = t % 4;
    src = W1 + s * H1D * H2D; dst = W1T + s * H2D * H1D; R = H1D; C = H2D;
  } else {                       // W2: 4 x 4 x 2
    int bb = b - 256; s = bb / 8; int t = bb % 8; dt = t / 2; ht = t % 2;
    src = W2 + s * H2D * H3D; dst = W2T + s * H3D * H2D; R = H2D; C = H3D;
  }
  int tx = threadIdx.x & 31, ty = threadIdx.x >> 5;
#pragma unroll
  for (int k = 0; k < 4; ++k)
    tile[ty + 8 * k][tx] = src[(size_t)(dt * 32 + ty + 8 * k) * C + ht * 32 + tx];
  __syncthreads();
#pragma unroll
  for (int k = 0; k < 4; ++k)
    dst[(size_t)(ht * 32 + ty + 8 * k) * R + dt * 32 + tx] = f2bf(tile[tx][ty + 8 * k]);
}

// R0 structure (proven): waves split the N dimension; x staged coalesced
// through double-buffered LDS; weight B-frags per-wave 32-col slices from L2.
// MT=32 halves LDS (17.7 KB) and per-wave registers -> ~6-8 blocks/CU
// (20-32 waves/CU vs 16 at MT=64): more phase-staggered blocks per CU to
// hide barrier drains and L2 weight-load latency. Tail is a non-atomic
// partial write (atomics were 1024 same-line RMWs per 64B out line).
__global__ __launch_bounds__(256, 4) void mlp_fused(
    const float* __restrict__ x, const int* __restrict__ species,
    const unsigned short* __restrict__ W0T, const unsigned short* __restrict__ W1T,
    const unsigned short* __restrict__ W2T,
    const float* __restrict__ b0, const float* __restrict__ b1,
    const float* __restrict__ b2, const float* __restrict__ W3,
    const float* __restrict__ b3, float* __restrict__ partial) {
  // 136-short row stride: 16B-aligned b128 reads, <=2-way bank aliasing (free).
  __shared__ __align__(16) unsigned short xbuf0[MT * 136];  // c0,c2; later H1
  __shared__ __align__(16) unsigned short xbuf1[MT * 136];  // c1;    later H0, then H2
  __shared__ float W3s[H3D];
  unsigned short* H0 = xbuf1;
  unsigned short* H1 = xbuf0;
  float* H2 = (float*)xbuf1;   // [32][68] fp32 = 8704 B (exactly xbuf1's size)

  const int a = blockIdx.x;          // atom-major: dense device-wide x footprint
  const int brow0 = blockIdx.y * MT;
  const int sp = species[a];
  const int tid = threadIdx.x;
  const int wave = tid >> 6;
  const int lane = tid & 63;
  const int q = lane >> 4;   // A/B k-quad, C/D row-quad
  const int r = lane & 15;   // A row / B col / C col

  const float4v zero = {0.f, 0.f, 0.f, 0.f};

  // staging coords: thread (srow16, c16) covers rows srow16+16h (h=0..1),
  // two 16B pieces per row per 128-float chunk -> 256B contiguous per 16 lanes
  const int srow16 = tid >> 4;
  const int c16 = tid & 15;
  const float* xbase = x + ((size_t)(brow0 + srow16) * A_DIM + a) * D_DIM + c16 * 4;
  unsigned short* xd0 = xbuf0 + srow16 * 136 + c16 * 4;
  unsigned short* xd1 = xbuf1 + srow16 * 136 + c16 * 4;
  const unsigned short* w0base =
      W0T + (size_t)sp * H1D * D_DIM + (wave * 32 + r) * D_DIM + q * 8;

  // ---- prologue: chunk 0 loads -> convert -> xbuf0 ----
  float4v xv[4];
#pragma unroll
  for (int h = 0; h < 2; ++h) {
    xv[2 * h]     = *(const float4v*)(xbase + (size_t)h * 16 * XROW);
    xv[2 * h + 1] = *(const float4v*)(xbase + (size_t)h * 16 * XROW + 64);
  }
  if (tid < H3D) W3s[tid] = W3[sp * H3D + tid];
  short8 bf[4][2];
#pragma unroll
  for (int kk = 0; kk < 4; ++kk)
#pragma unroll
    for (int n = 0; n < 2; ++n)
      bf[kk][n] = *(const short8*)(w0base + n * 16 * D_DIM + kk * 32);
#pragma unroll
  for (int h = 0; h < 2; ++h) {
    store_bf4(xd0 + h * 16 * 136, xv[2 * h]);
    store_bf4(xd0 + h * 16 * 136 + 64, xv[2 * h + 1]);
  }
  __syncthreads();   // (b0) xbuf0 published

  float4v acc0[2][2];
#pragma unroll
  for (int g = 0; g < 2; ++g) { acc0[g][0] = zero; acc0[g][1] = zero; }

  // ---- chunk 0: chunk-1 x loads issued first, then MFMA on xbuf0 ----
#pragma unroll
  for (int h = 0; h < 2; ++h) {
    xv[2 * h]     = *(const float4v*)(xbase + (size_t)h * 16 * XROW + 128);
    xv[2 * h + 1] = *(const float4v*)(xbase + (size_t)h * 16 * XROW + 192);
  }
#pragma unroll
  for (int g = 0; g < 2; ++g)
#pragma unroll
    for (int kk = 0; kk < 4; ++kk) {
      short8 af = *(const short8*)(xbuf0 + (g * 16 + r) * 136 + kk * 32 + q * 8);
      acc0[g][0] = __builtin_amdgcn_mfma_f32_16x16x32_bf16(af, bf[kk][0], acc0[g][0], 0, 0, 0);
      acc0[g][1] = __builtin_amdgcn_mfma_f32_16x16x32_bf16(af, bf[kk][1], acc0[g][1], 0, 0, 0);
    }
#pragma unroll
  for (int h = 0; h < 2; ++h) {
    store_bf4(xd1 + h * 16 * 136, xv[2 * h]);
    store_bf4(xd1 + h * 16 * 136 + 64, xv[2 * h + 1]);
  }
  __syncthreads();   // (b1) xbuf1 published

  // ---- chunk 1: bf(c1) first, then chunk-2 x loads ----
#pragma unroll
  for (int kk = 0; kk < 4; ++kk)
#pragma unroll
    for (int n = 0; n < 2; ++n)
      bf[kk][n] = *(const short8*)(w0base + n * 16 * D_DIM + 128 + kk * 32);
#pragma unroll
  for (int h = 0; h < 2; ++h) {
    xv[2 * h]     = *(const float4v*)(xbase + (size_t)h * 16 * XROW + 256);
    xv[2 * h + 1] = *(const float4v*)(xbase + (size_t)h * 16 * XROW + 320);
  }
#pragma unroll
  for (int g = 0; g < 2; ++g)
#pragma unroll
    for (int kk = 0; kk < 4; ++kk) {
      short8 af = *(const short8*)(xbuf1 + (g * 16 + r) * 136 + kk * 32 + q * 8);
      acc0[g][0] = __builtin_amdgcn_mfma_f32_16x16x32_bf16(af, bf[kk][0], acc0[g][0], 0, 0, 0);
      acc0[g][1] = __builtin_amdgcn_mfma_f32_16x16x32_bf16(af, bf[kk][1], acc0[g][1], 0, 0, 0);
    }
#pragma unroll
  for (int h = 0; h < 2; ++h) {
    store_bf4(xd0 + h * 16 * 136, xv[2 * h]);
    store_bf4(xd0 + h * 16 * 136 + 64, xv[2 * h + 1]);
  }
  __syncthreads();   // (b2) xbuf0 re-published (chunk 2)

  // ---- chunk 2: MFMA on xbuf0 ----
#pragma unroll
  for (int kk = 0; kk < 4; ++kk)
#pragma unroll
    for (int n = 0; n < 2; ++n)
      bf[kk][n] = *(const short8*)(w0base + n * 16 * D_DIM + 256 + kk * 32);
#pragma unroll
  for (int g = 0; g < 2; ++g)
#pragma unroll
    for (int kk = 0; kk < 4; ++kk) {
      short8 af = *(const short8*)(xbuf0 + (g * 16 + r) * 136 + kk * 32 + q * 8);
      acc0[g][0] = __builtin_amdgcn_mfma_f32_16x16x32_bf16(af, bf[kk][0], acc0[g][0], 0, 0, 0);
      acc0[g][1] = __builtin_amdgcn_mfma_f32_16x16x32_bf16(af, bf[kk][1], acc0[g][1], 0, 0, 0);
    }
  // H0 (=xbuf1) writes: xbuf1's last reads drained at (b2); chunk-2 MFMA of
  // other waves touches only xbuf0 -> no barrier needed here.
  {
    const float* b0p = b0 + sp * H1D;
#pragma unroll
    for (int n = 0; n < 2; ++n) {
      float bias = b0p[wave * 32 + n * 16 + r];
#pragma unroll
      for (int g = 0; g < 2; ++g)
#pragma unroll
        for (int i = 0; i < 4; ++i) {
          float y = acc0[g][n][i] + bias;
          H0[(g * 16 + q * 4 + i) * 136 + wave * 32 + n * 16 + r] = f2bf(__expf(-y * y));
        }
    }
  }
  __syncthreads();   // (b3) H0 published; xbuf0 free

  // ---------------- layer 1: [32x128] @ [128x128]; H0 -> H1 (=xbuf0) ----------------
  {
    float4v acc1[2][2];
#pragma unroll
    for (int g = 0; g < 2; ++g) { acc1[g][0] = zero; acc1[g][1] = zero; }
    const unsigned short* w1base =
        W1T + (size_t)sp * H2D * H1D + (wave * 32 + r) * H1D + q * 8;
    short8 wf[4][2];
#pragma unroll
    for (int kk = 0; kk < 4; ++kk)
#pragma unroll
      for (int n = 0; n < 2; ++n)
        wf[kk][n] = *(const short8*)(w1base + n * 16 * H1D + kk * 32);
#pragma unroll
    for (int g = 0; g < 2; ++g)
#pragma unroll
      for (int kk = 0; kk < 4; ++kk) {
        short8 af = *(const short8*)(H0 + (g * 16 + r) * 136 + kk * 32 + q * 8);
        acc1[g][0] = __builtin_amdgcn_mfma_f32_16x16x32_bf16(af, wf[kk][0], acc1[g][0], 0, 0, 0);
        acc1[g][1] = __builtin_amdgcn_mfma_f32_16x16x32_bf16(af, wf[kk][1], acc1[g][1], 0, 0, 0);
      }
    const float* b1p = b1 + sp * H2D;
#pragma unroll
    for (int n = 0; n < 2; ++n) {
      float bias = b1p[wave * 32 + n * 16 + r];
#pragma unroll
      for (int g = 0; g < 2; ++g)
#pragma unroll
        for (int i = 0; i < 4; ++i) {
          float y = acc1[g][n][i] + bias;
          H1[(g * 16 + q * 4 + i) * 136 + wave * 32 + n * 16 + r] = f2bf(__expf(-y * y));
        }
    }
  }
  __syncthreads();   // (b4) H1 published; all H0 reads done

  // ---------------- layer 2: [32x128] @ [128x64]; H1 -> H2 (=xbuf1) ----------------
  {
    float4v acc2[2];
    acc2[0] = zero; acc2[1] = zero;
    const unsigned short* w2base =
        W2T + (size_t)sp * H3D * H2D + (wave * 16 + r) * H2D + q * 8;
    short8 wf[4];
#pragma unroll
    for (int kk = 0; kk < 4; ++kk)
      wf[kk] = *(const short8*)(w2base + kk * 32);
#pragma unroll
    for (int g = 0; g < 2; ++g)
#pragma unroll
      for (int kk = 0; kk < 4; ++kk) {
        short8 af = *(const short8*)(H1 + (g * 16 + r) * 136 + kk * 32 + q * 8);
        acc2[g] = __builtin_amdgcn_mfma_f32_16x16x32_bf16(af, wf[kk], acc2[g], 0, 0, 0);
      }
    float bias = b2[sp * H3D + wave * 16 + r];
#pragma unroll
    for (int g = 0; g < 2; ++g)
#pragma unroll
      for (int i = 0; i < 4; ++i) {
        float y = acc2[g][i] + bias;
        H2[(g * 16 + q * 4 + i) * 68 + wave * 16 + r] = __expf(-y * y);
      }
  }
  __syncthreads();   // (b5) H2 published

  // -------- layer 3: dot with W3[64]; non-atomic partial write --------
  // 8 threads per row x 32 rows = all 256 threads; one coalesced 128B store.
  {
    const int row = tid >> 3;        // 0..31
    const int seg = tid & 7;         // 8 floats each
    const float4v* h2p = (const float4v*)(H2 + row * 68 + seg * 8);
    const float4v* w3p = (const float4v*)(W3s + seg * 8);
    float4v sv = h2p[0] * w3p[0] + h2p[1] * w3p[1];
    float s = sv[0] + sv[1] + sv[2] + sv[3];
    s += __shfl_xor(s, 1);
    s += __shfl_xor(s, 2);
    s += __shfl_xor(s, 4);
    if (seg == 0) partial[(size_t)a * B_DIM + brow0 + row] = s + b3[sp];
  }
}

// out[b] = sum_a partial[a][b]; 512 KB read (L2-hot), 8 KB write.
__global__ __launch_bounds__(256) void reduce_partial(
    const float* __restrict__ p, float* __restrict__ out) {
  const int b = blockIdx.x * 256 + threadIdx.x;
  float s = 0.f;
#pragma unroll
  for (int a = 0; a < A_DIM; ++a) s += p[(size_t)a * B_DIM + b];
  out[b] = s;
}

extern "C" void kernel_launch(void* const* d_in, const int* in_sizes, int n_in,
                              void* d_out, int out_size, void* d_ws, size_t ws_size,
                              hipStream_t stream) {
  const float* x       = (const float*)d_in[0];
  const int*   species = (const int*)d_in[1];
  const float* W0 = (const float*)d_in[2];
  const float* b0 = (const float*)d_in[3];
  const float* W1 = (const float*)d_in[4];
  const float* b1 = (const float*)d_in[5];
  const float* W2 = (const float*)d_in[6];
  const float* b2 = (const float*)d_in[7];
  const float* W3 = (const float*)d_in[8];
  const float* b3 = (const float*)d_in[9];
  float* out = (float*)d_out;

  unsigned short* W0T = (unsigned short*)d_ws;
  unsigned short* W1T = W0T + S_DIM * H1D * D_DIM;
  unsigned short* W2T = W1T + S_DIM * H2D * H1D;
  float* partial = (float*)(W2T + S_DIM * H3D * H2D);   // [A_DIM][B_DIM] fp32

  prep_weights<<<dim3(288), dim3(256), 0, stream>>>(W0, W1, W2, W0T, W1T, W2T);
  mlp_fused<<<dim3(A_DIM, B_DIM / MT), dim3(256), 0, stream>>>(
      x, species, W0T, W1T, W2T, b0, b1, b2, W3, b3, partial);
  reduce_partial<<<dim3(B_DIM / 256), dim3(256), 0, stream>>>(partial, out);
}